// Round 5
// baseline (443.909 us; speedup 1.0000x reference)
//
#include <hip/hip_runtime.h>

// ---- types ----
typedef __bf16 bf16x8 __attribute__((ext_vector_type(8)));
typedef float f32x4 __attribute__((ext_vector_type(4)));
typedef unsigned short ushort8 __attribute__((ext_vector_type(8)));
typedef unsigned short ushort4v __attribute__((ext_vector_type(4)));
typedef unsigned int uint4v __attribute__((ext_vector_type(4)));

union Frag {
  ushort8 u;
  bf16x8 b;
  uint4v w;
};

__device__ __forceinline__ unsigned short f2bf(float f) {
  unsigned int u = __float_as_uint(f);
  u += 0x7fffu + ((u >> 16) & 1u);   // RNE; inputs are finite
  return (unsigned short)(u >> 16);
}

__device__ __forceinline__ f32x4 fz4() {
  f32x4 v; v[0] = 0.f; v[1] = 0.f; v[2] = 0.f; v[3] = 0.f; return v;
}

#define MFMA16(a, b, c) __builtin_amdgcn_mfma_f32_16x16x32_bf16(a, b, c, 0, 0, 0)

// Sizes: B=8, C=256, N=4096 (64x64), IC=128. OUTPUT FP32 (32 MiB).
// Slab (ushort): theta/phi/out_nm = 4096*128 = 524288; gT = 128*4096 = 524288.

// ---------------- prep: weights fp32 -> bf16 ----------------
__global__ void k_prep(const float* __restrict__ wg, const float* __restrict__ wt,
                       const float* __restrict__ wp, const float* __restrict__ wm,
                       unsigned short* __restrict__ wcat, unsigned short* __restrict__ wmb) {
  int t = blockIdx.x * 256 + threadIdx.x;
  if (t < 98304) {
    int o = t >> 8;
    const float* src = (o < 128) ? wt : ((o < 256) ? wp : wg);
    wcat[t] = f2bf(src[(o & 127) * 256 + (t & 255)]);
  }
  if (t < 32768) wmb[t] = f2bf(wm[t]);
}

// ---- shared staging: x[bx][c][pt0..pt0+64) -> xb[p][c] bf16, row stride 264 ----
__device__ __forceinline__ void stage_x(const float* __restrict__ x, int bx, int pt0,
                                        unsigned short* xb, int tid) {
  int c0 = (tid >> 2) * 4;
  int psub = (tid & 3) * 16;
  const float* xbase = x + (size_t)bx * 256 * 4096 + pt0;
  for (int ppc = 0; ppc < 4; ++ppc) {
    int p0 = psub + ppc * 4;
    f32x4 r0 = *(const f32x4*)(xbase + (size_t)(c0 + 0) * 4096 + p0);
    f32x4 r1 = *(const f32x4*)(xbase + (size_t)(c0 + 1) * 4096 + p0);
    f32x4 r2 = *(const f32x4*)(xbase + (size_t)(c0 + 2) * 4096 + p0);
    f32x4 r3 = *(const f32x4*)(xbase + (size_t)(c0 + 3) * 4096 + p0);
    for (int e = 0; e < 4; ++e) {
      ushort4v wv;
      wv[0] = f2bf(r0[e]); wv[1] = f2bf(r1[e]); wv[2] = f2bf(r2[e]); wv[3] = f2bf(r3[e]);
      *(ushort4v*)&xb[(p0 + e) * 264 + c0] = wv;
    }
  }
}

// ---------------- proj theta+phi ----------------
__global__ __launch_bounds__(256, 2) void k_proj_tp(
    const float* __restrict__ x, const unsigned short* __restrict__ wcat,
    const float* __restrict__ bt, const float* __restrict__ bp,
    unsigned short* __restrict__ theta, unsigned short* __restrict__ phi,
    int bx0, int sb) {
  __shared__ unsigned short xb[64 * 264];
  int gb = blockIdx.x >> 6;
  int bx = bx0 + gb;
  size_t ob_off = (size_t)gb * sb;
  int pt0 = (blockIdx.x & 63) << 6;
  int tid = threadIdx.x;
  stage_x(x, bx, pt0, xb, tid);
  __syncthreads();
  int l = tid & 63, w = tid >> 6, lr = l & 15, lg = l >> 4;
  int obase = w * 64;
  f32x4 acc[4][4];
  for (int i = 0; i < 4; ++i) for (int j = 0; j < 4; ++j) acc[i][j] = fz4();
  for (int kc = 0; kc < 8; ++kc) {
    int ko = kc * 32 + 8 * lg;
    Frag wa[4], xq[4];
    for (int ot = 0; ot < 4; ++ot)
      wa[ot].u = *(const ushort8*)(wcat + (size_t)(obase + ot * 16 + lr) * 256 + ko);
    for (int pt = 0; pt < 4; ++pt)
      xq[pt].u = *(const ushort8*)&xb[(pt * 16 + lr) * 264 + ko];
    for (int ot = 0; ot < 4; ++ot)
      for (int pt = 0; pt < 4; ++pt)
        acc[ot][pt] = MFMA16(wa[ot].b, xq[pt].b, acc[ot][pt]);
  }
  for (int ot = 0; ot < 4; ++ot) {
    int o0 = obase + ot * 16 + 4 * lg;   // D row = (lane>>4)*4 + reg
    float bias[4];
    for (int j = 0; j < 4; ++j) bias[j] = (o0 < 128) ? bt[o0 + j] : bp[o0 + j - 128];
    unsigned short* dst = (o0 < 128) ? theta : phi;
    int oc = o0 & 127;
    for (int pt = 0; pt < 4; ++pt) {
      int n = pt0 + pt * 16 + lr;        // D col = lane&15
      ushort4v wv;
      for (int j = 0; j < 4; ++j) {
        float v = acc[ot][pt][j] + bias[j];
        wv[j] = f2bf(v > 0.f ? v : 0.f);
      }
      *(ushort4v*)(dst + ob_off + (size_t)n * 128 + oc) = wv;
    }
  }
}

// ---------------- proj g (transposed out): gT[o][n] ----------------
__global__ __launch_bounds__(256, 2) void k_proj_g(
    const float* __restrict__ x, const unsigned short* __restrict__ wcat,
    const float* __restrict__ bg, unsigned short* __restrict__ gT,
    int bx0, int sb) {
  __shared__ unsigned short xb[64 * 264];
  int gb = blockIdx.x >> 6;
  int bx = bx0 + gb;
  size_t ob_off = (size_t)gb * sb;
  int pt0 = (blockIdx.x & 63) << 6;
  int tid = threadIdx.x;
  stage_x(x, bx, pt0, xb, tid);
  __syncthreads();
  int l = tid & 63, w = tid >> 6, lr = l & 15, lg = l >> 4;
  f32x4 acc[8];
  for (int i = 0; i < 8; ++i) acc[i] = fz4();
  for (int kc = 0; kc < 8; ++kc) {
    int ko = kc * 32 + 8 * lg;
    Frag xa;
    xa.u = *(const ushort8*)&xb[(w * 16 + lr) * 264 + ko];
    for (int ot = 0; ot < 8; ++ot) {
      Frag wb;
      wb.u = *(const ushort8*)(wcat + (size_t)(256 + ot * 16 + lr) * 256 + ko);
      acc[ot] = MFMA16(xa.b, wb.b, acc[ot]);
    }
  }
  for (int ot = 0; ot < 8; ++ot) {
    int o = ot * 16 + lr;                 // D col = channel
    float bias = bg[o];
    int n0 = pt0 + w * 16 + 4 * lg;       // D rows = position
    ushort4v wv;
    for (int j = 0; j < 4; ++j) {
      float v = acc[ot][j] + bias;
      wv[j] = f2bf(v > 0.f ? v : 0.f);
    }
    *(ushort4v*)(gT + ob_off + (size_t)o * 4096 + n0) = wv;
  }
}

// ---------------- fused flash attention ----------------
__global__ __launch_bounds__(128, 2) void k_attn(
    const unsigned short* __restrict__ theta, const unsigned short* __restrict__ phi,
    const unsigned short* __restrict__ gT, unsigned short* __restrict__ out_nm,
    int sb) {
  __shared__ unsigned short phs[32 * 136];   // phi tile [32 kv][128+8]
  __shared__ unsigned short gts[128 * 40];   // gT tile  [128 d][32+8]
  int gb = blockIdx.x >> 6;
  size_t boff = (size_t)gb * sb;
  int q0 = (blockIdx.x & 63) << 6;
  int tid = threadIdx.x;
  int l = tid & 63, w = tid >> 6, lr = l & 15, lg = l >> 4;
  int qb0 = q0 + w * 32;

  Frag qf[2][4];
  for (int qq = 0; qq < 2; ++qq)
    for (int kc = 0; kc < 4; ++kc)
      qf[qq][kc].u = *(const ushort8*)(theta + boff +
          (size_t)(qb0 + qq * 16 + lr) * 128 + kc * 32 + 8 * lg);

  f32x4 oacc[2][8];
  for (int q = 0; q < 2; ++q) for (int d = 0; d < 8; ++d) oacc[q][d] = fz4();
  float m[2] = {-1e30f, -1e30f}, sden[2] = {0.f, 0.f};

  for (int kb = 0; kb < 128; ++kb) {
    int kv0 = kb * 32;
    __syncthreads();
    // phi tile: 32 rows x 128 ushorts = 512 chunks of 8
    for (int i = tid; i < 512; i += 128) {
      int row = i >> 4, c8 = (i & 15) * 8;
      *(ushort8*)&phs[row * 136 + c8] =
          *(const ushort8*)(phi + boff + (size_t)(kv0 + row) * 128 + c8);
    }
    // gT tile: 128 rows x 32 ushorts = 512 chunks of 8
    for (int i = tid; i < 512; i += 128) {
      int row = i >> 2, c8 = (i & 3) * 8;
      *(ushort8*)&gts[row * 40 + c8] =
          *(const ushort8*)(gT + boff + (size_t)row * 4096 + kv0 + c8);
    }
    __syncthreads();

    // S^T = phi_tile (A) x theta (B): D[kv][q]
    f32x4 sacc[2][2];
    sacc[0][0] = fz4(); sacc[0][1] = fz4(); sacc[1][0] = fz4(); sacc[1][1] = fz4();
    for (int kc = 0; kc < 4; ++kc) {
      Frag a0, a1;
      a0.u = *(const ushort8*)&phs[lr * 136 + kc * 32 + 8 * lg];
      a1.u = *(const ushort8*)&phs[(lr + 16) * 136 + kc * 32 + 8 * lg];
      sacc[0][0] = MFMA16(a0.b, qf[0][kc].b, sacc[0][0]);
      sacc[1][0] = MFMA16(a0.b, qf[1][kc].b, sacc[1][0]);
      sacc[0][1] = MFMA16(a1.b, qf[0][kc].b, sacc[0][1]);
      sacc[1][1] = MFMA16(a1.b, qf[1][kc].b, sacc[1][1]);
    }

    Frag bw[2];
    for (int qq = 0; qq < 2; ++qq) {
      float s[8];
      for (int j = 0; j < 4; ++j) { s[j] = sacc[qq][0][j]; s[4 + j] = sacc[qq][1][j]; }
      float mt = s[0];
      for (int j = 1; j < 8; ++j) mt = fmaxf(mt, s[j]);
      mt = fmaxf(mt, __shfl_xor(mt, 16));
      mt = fmaxf(mt, __shfl_xor(mt, 32));
      if (!__all(mt <= m[qq] + 8.0f)) {        // defer-rescale (T13)
        float mn = fmaxf(m[qq], mt);
        float sc = __expf(m[qq] - mn);
        sden[qq] *= sc;
        for (int dt = 0; dt < 8; ++dt) oacc[qq][dt] *= sc;
        m[qq] = mn;
      }
      float p[8], ps = 0.f;
      for (int j = 0; j < 8; ++j) { p[j] = __expf(s[j] - m[qq]); ps += p[j]; }
      ps += __shfl_xor(ps, 16);
      ps += __shfl_xor(ps, 32);
      sden[qq] += ps;
      // pack P (lane holds kv = 16*nb + 4*lg + j, q col = lr)
      unsigned int pw[4];
      for (int nb = 0; nb < 2; ++nb)
        for (int wd = 0; wd < 2; ++wd)
          pw[nb * 2 + wd] = (unsigned)f2bf(p[nb * 4 + 2 * wd]) |
                            ((unsigned)f2bf(p[nb * 4 + 2 * wd + 1]) << 16);
      // redistribute to B-frag layout: lane needs kv = 8*lg + e
      int src0 = lr | (((2 * lg) & 3) << 4);
      int src1 = lr | (((2 * lg + 1) & 3) << 4);
      int bt_ = lg >> 1;
      unsigned a0 = (unsigned)__shfl((int)pw[0], src0), a1 = (unsigned)__shfl((int)pw[1], src0),
               a2 = (unsigned)__shfl((int)pw[2], src0), a3 = (unsigned)__shfl((int)pw[3], src0);
      unsigned c0 = (unsigned)__shfl((int)pw[0], src1), c1 = (unsigned)__shfl((int)pw[1], src1),
               c2 = (unsigned)__shfl((int)pw[2], src1), c3 = (unsigned)__shfl((int)pw[3], src1);
      bw[qq].w[0] = bt_ ? a2 : a0;
      bw[qq].w[1] = bt_ ? a3 : a1;
      bw[qq].w[2] = bt_ ? c2 : c0;
      bw[qq].w[3] = bt_ ? c3 : c1;
    }

    // O^T += V^T (A) x P^T (B): D[d][q]
    for (int dt = 0; dt < 8; ++dt) {
      Frag vf;
      vf.u = *(const ushort8*)&gts[(dt * 16 + lr) * 40 + 8 * lg];
      oacc[0][dt] = MFMA16(vf.b, bw[0].b, oacc[0][dt]);
      oacc[1][dt] = MFMA16(vf.b, bw[1].b, oacc[1][dt]);
    }
  }

  for (int qq = 0; qq < 2; ++qq) {
    float inv = 1.0f / sden[qq];
    size_t base = boff + (size_t)(qb0 + qq * 16 + lr) * 128;
    for (int dt = 0; dt < 8; ++dt) {
      ushort4v wv;
      for (int j = 0; j < 4; ++j) wv[j] = f2bf(oacc[qq][dt][j] * inv);
      *(ushort4v*)(out_nm + base + dt * 16 + 4 * lg) = wv;
    }
  }
}

// ---------------- mask GEMM + bias + relu + residual (fp32 out) ----------------
__global__ __launch_bounds__(256, 2) void k_mask(
    const unsigned short* __restrict__ wmb, const unsigned short* __restrict__ out_nm,
    const float* __restrict__ bm, const float* __restrict__ x,
    float* __restrict__ out, int bx0, int sb) {
  int gb = blockIdx.x >> 6;
  int bx = bx0 + gb;
  size_t boff = (size_t)gb * sb;
  int n0 = (blockIdx.x & 63) << 6;
  int tid = threadIdx.x;
  int l = tid & 63, w = tid >> 6, lr = l & 15, lg = l >> 4;
  int ob = w * 64;
  f32x4 acc[4][4];
  for (int i = 0; i < 4; ++i) for (int j = 0; j < 4; ++j) acc[i][j] = fz4();
  for (int kc = 0; kc < 4; ++kc) {
    int ko = kc * 32 + 8 * lg;
    Frag wa[4], xq[4];
    for (int ot = 0; ot < 4; ++ot)
      wa[ot].u = *(const ushort8*)(wmb + (size_t)(ob + ot * 16 + lr) * 128 + ko);
    for (int nt = 0; nt < 4; ++nt)
      xq[nt].u = *(const ushort8*)(out_nm + boff + (size_t)(n0 + nt * 16 + lr) * 128 + ko);
    for (int ot = 0; ot < 4; ++ot)
      for (int nt = 0; nt < 4; ++nt)
        acc[ot][nt] = MFMA16(wa[ot].b, xq[nt].b, acc[ot][nt]);
  }
  for (int ot = 0; ot < 4; ++ot) {
    int o0 = ob + ot * 16 + 4 * lg;
    for (int nt = 0; nt < 4; ++nt) {
      int n = n0 + nt * 16 + lr;
      for (int j = 0; j < 4; ++j) {
        size_t idx = ((size_t)(bx << 8) + o0 + j) * 4096 + n;
        float v = acc[ot][nt][j] + bm[o0 + j];
        v = v > 0.f ? v : 0.f;
        out[idx] = v + x[idx];
      }
    }
  }
}

extern "C" void kernel_launch(void* const* d_in, const int* in_sizes, int n_in,
                              void* d_out, int out_size, void* d_ws, size_t ws_size,
                              hipStream_t stream) {
  const float* x  = (const float*)d_in[0];
  const float* wg = (const float*)d_in[1];
  const float* bg = (const float*)d_in[2];
  const float* wt = (const float*)d_in[3];
  const float* bt = (const float*)d_in[4];
  const float* wp = (const float*)d_in[5];
  const float* bp = (const float*)d_in[6];
  const float* wm = (const float*)d_in[7];
  const float* bm = (const float*)d_in[8];
  float* out = (float*)d_out;           // OUTPUT IS FP32 (32 MiB)

  const size_t SLAB = 524288;           // ushorts per batch slab (1 MB)
  const size_t FAST_NEED = (98304 + 32768 + 3 * 8 * SLAB) * 2;  // 25.4 MB

  if (ws_size >= FAST_NEED) {
    // ---- FAST: all scratch in ws; d_out untouched until k_mask ----
    unsigned short* wcat  = (unsigned short*)d_ws;
    unsigned short* wmb   = wcat + 98304;
    unsigned short* theta = wmb + 32768;
    unsigned short* phi   = theta + 8 * SLAB;
    unsigned short* gT    = phi + 8 * SLAB;
    k_prep<<<384, 256, 0, stream>>>(wg, wt, wp, wm, wcat, wmb);
    k_proj_tp<<<512, 256, 0, stream>>>(x, wcat, bt, bp, theta, phi, 0, (int)SLAB);
    k_proj_g<<<512, 256, 0, stream>>>(x, wcat, bg, gT, 0, (int)SLAB);
    k_attn<<<512, 128, 0, stream>>>(theta, phi, gT, theta /*alias*/, (int)SLAB);
    k_mask<<<512, 256, 0, stream>>>(wmb, theta, bm, x, out, 0, (int)SLAB);
  } else {
    // ---- SAFE: ws = weights + bounce (1.25 MB); big scratch inside d_out ----
    // d_out = 16,777,216 ushorts. out_nm[b] at b*SLAB (b=1..7, ends 4.19M);
    // theta/phi/gT slabs at 12,582,912.. (ends 14,155,776). Masks descend 7..0:
    // mask b writes ushort [b*2097152, +2097152), covering only out_nm[s],
    // s in [4b, 4b+4) -> s > b already consumed; batch-0 out_nm bounces via ws.
    unsigned short* wcat   = (unsigned short*)d_ws;
    unsigned short* wmb    = wcat + 98304;
    unsigned short* bounce = wmb + 32768;
    unsigned short* dob    = (unsigned short*)d_out;
    unsigned short* theta_s = dob + 12582912;
    unsigned short* phi_s   = theta_s + SLAB;
    unsigned short* gT_s    = phi_s + SLAB;

    k_prep<<<384, 256, 0, stream>>>(wg, wt, wp, wm, wcat, wmb);
    for (int b = 0; b < 8; ++b) {
      unsigned short* onm = (b == 0) ? bounce : dob + (size_t)b * SLAB;
      k_proj_tp<<<64, 256, 0, stream>>>(x, wcat, bt, bp, theta_s, phi_s, b, 0);
      k_proj_g<<<64, 256, 0, stream>>>(x, wcat, bg, gT_s, b, 0);
      k_attn<<<64, 128, 0, stream>>>(theta_s, phi_s, gT_s, onm, 0);
    }
    for (int b = 7; b >= 0; --b) {
      unsigned short* onm = (b == 0) ? bounce : dob + (size_t)b * SLAB;
      k_mask<<<64, 256, 0, stream>>>(wmb, onm, bm, x, out, b, 0);
    }
  }
}

// Round 6
// 318.006 us; speedup vs baseline: 1.3959x; 1.3959x over previous
//
#include <hip/hip_runtime.h>

// ---- types ----
typedef __bf16 bf16x8 __attribute__((ext_vector_type(8)));
typedef float f32x4 __attribute__((ext_vector_type(4)));
typedef unsigned short ushort8 __attribute__((ext_vector_type(8)));
typedef unsigned short ushort4v __attribute__((ext_vector_type(4)));
typedef unsigned int uint4v __attribute__((ext_vector_type(4)));

union Frag {
  ushort8 u;
  bf16x8 b;
  uint4v w;
};

__device__ __forceinline__ unsigned short f2bf(float f) {
  unsigned int u = __float_as_uint(f);
  u += 0x7fffu + ((u >> 16) & 1u);   // RNE; inputs are finite
  return (unsigned short)(u >> 16);
}

__device__ __forceinline__ f32x4 fz4() {
  f32x4 v; v[0] = 0.f; v[1] = 0.f; v[2] = 0.f; v[3] = 0.f; return v;
}

#define MFMA16(a, b, c) __builtin_amdgcn_mfma_f32_16x16x32_bf16(a, b, c, 0, 0, 0)

// Sizes: B=8, C=256, N=4096 (64x64), IC=128. OUTPUT FP32 (32 MiB).
// ws (ushort): wcat 98304 | wmb 32768 | theta 8*524288 | phi 8*524288 | gT 8*524288
// (FAST layout confirmed working round 5: ws_size >= 25.4 MB.)

// ---------------- prep: weights fp32 -> bf16 ----------------
__global__ void k_prep(const float* __restrict__ wg, const float* __restrict__ wt,
                       const float* __restrict__ wp, const float* __restrict__ wm,
                       unsigned short* __restrict__ wcat, unsigned short* __restrict__ wmb) {
  int t = blockIdx.x * 256 + threadIdx.x;
  if (t < 98304) {
    int o = t >> 8;
    const float* src = (o < 128) ? wt : ((o < 256) ? wp : wg);
    wcat[t] = f2bf(src[(o & 127) * 256 + (t & 255)]);
  }
  if (t < 32768) wmb[t] = f2bf(wm[t]);
}

// ---- shared staging: x[bx][c][pt0..pt0+64) -> xb[p][c] bf16, row stride 264 ----
__device__ __forceinline__ void stage_x(const float* __restrict__ x, int bx, int pt0,
                                        unsigned short* xb, int tid) {
  int c0 = (tid >> 2) * 4;
  int psub = (tid & 3) * 16;
  const float* xbase = x + (size_t)bx * 256 * 4096 + pt0;
  for (int ppc = 0; ppc < 4; ++ppc) {
    int p0 = psub + ppc * 4;
    f32x4 r0 = *(const f32x4*)(xbase + (size_t)(c0 + 0) * 4096 + p0);
    f32x4 r1 = *(const f32x4*)(xbase + (size_t)(c0 + 1) * 4096 + p0);
    f32x4 r2 = *(const f32x4*)(xbase + (size_t)(c0 + 2) * 4096 + p0);
    f32x4 r3 = *(const f32x4*)(xbase + (size_t)(c0 + 3) * 4096 + p0);
    for (int e = 0; e < 4; ++e) {
      ushort4v wv;
      wv[0] = f2bf(r0[e]); wv[1] = f2bf(r1[e]); wv[2] = f2bf(r2[e]); wv[3] = f2bf(r3[e]);
      *(ushort4v*)&xb[(p0 + e) * 264 + c0] = wv;
    }
  }
}

// ---------------- proj theta+phi ----------------
__global__ __launch_bounds__(256, 2) void k_proj_tp(
    const float* __restrict__ x, const unsigned short* __restrict__ wcat,
    const float* __restrict__ bt, const float* __restrict__ bp,
    unsigned short* __restrict__ theta, unsigned short* __restrict__ phi) {
  __shared__ unsigned short xb[64 * 264];
  int gb = blockIdx.x >> 6;
  size_t ob_off = (size_t)gb * 524288;
  int pt0 = (blockIdx.x & 63) << 6;
  int tid = threadIdx.x;
  stage_x(x, gb, pt0, xb, tid);
  __syncthreads();
  int l = tid & 63, w = tid >> 6, lr = l & 15, lg = l >> 4;
  int obase = w * 64;
  f32x4 acc[4][4];
  for (int i = 0; i < 4; ++i) for (int j = 0; j < 4; ++j) acc[i][j] = fz4();
  for (int kc = 0; kc < 8; ++kc) {
    int ko = kc * 32 + 8 * lg;
    Frag wa[4], xq[4];
    for (int ot = 0; ot < 4; ++ot)
      wa[ot].u = *(const ushort8*)(wcat + (size_t)(obase + ot * 16 + lr) * 256 + ko);
    for (int pt = 0; pt < 4; ++pt)
      xq[pt].u = *(const ushort8*)&xb[(pt * 16 + lr) * 264 + ko];
    for (int ot = 0; ot < 4; ++ot)
      for (int pt = 0; pt < 4; ++pt)
        acc[ot][pt] = MFMA16(wa[ot].b, xq[pt].b, acc[ot][pt]);
  }
  for (int ot = 0; ot < 4; ++ot) {
    int o0 = obase + ot * 16 + 4 * lg;   // D row = (lane>>4)*4 + reg
    float bias[4];
    for (int j = 0; j < 4; ++j) bias[j] = (o0 < 128) ? bt[o0 + j] : bp[o0 + j - 128];
    unsigned short* dst = (o0 < 128) ? theta : phi;
    int oc = o0 & 127;
    for (int pt = 0; pt < 4; ++pt) {
      int n = pt0 + pt * 16 + lr;        // D col = lane&15
      ushort4v wv;
      for (int j = 0; j < 4; ++j) {
        float v = acc[ot][pt][j] + bias[j];
        wv[j] = f2bf(v > 0.f ? v : 0.f);
      }
      *(ushort4v*)(dst + ob_off + (size_t)n * 128 + oc) = wv;
    }
  }
}

// ---------------- proj g (transposed out): gT[o][n] ----------------
__global__ __launch_bounds__(256, 2) void k_proj_g(
    const float* __restrict__ x, const unsigned short* __restrict__ wcat,
    const float* __restrict__ bg, unsigned short* __restrict__ gT) {
  __shared__ unsigned short xb[64 * 264];
  int gb = blockIdx.x >> 6;
  size_t ob_off = (size_t)gb * 524288;
  int pt0 = (blockIdx.x & 63) << 6;
  int tid = threadIdx.x;
  stage_x(x, gb, pt0, xb, tid);
  __syncthreads();
  int l = tid & 63, w = tid >> 6, lr = l & 15, lg = l >> 4;
  f32x4 acc[8];
  for (int i = 0; i < 8; ++i) acc[i] = fz4();
  for (int kc = 0; kc < 8; ++kc) {
    int ko = kc * 32 + 8 * lg;
    Frag xa;
    xa.u = *(const ushort8*)&xb[(w * 16 + lr) * 264 + ko];
    for (int ot = 0; ot < 8; ++ot) {
      Frag wb;
      wb.u = *(const ushort8*)(wcat + (size_t)(256 + ot * 16 + lr) * 256 + ko);
      acc[ot] = MFMA16(xa.b, wb.b, acc[ot]);
    }
  }
  for (int ot = 0; ot < 8; ++ot) {
    int o = ot * 16 + lr;                 // D col = channel
    float bias = bg[o];
    int n0 = pt0 + w * 16 + 4 * lg;       // D rows = position
    ushort4v wv;
    for (int j = 0; j < 4; ++j) {
      float v = acc[ot][j] + bias;
      wv[j] = f2bf(v > 0.f ? v : 0.f);
    }
    *(ushort4v*)(gT + ob_off + (size_t)o * 4096 + n0) = wv;
  }
}

// ---------------- fused flash attention, KV-split-4, no-LDS main loop --------
// Block = 32 q-rows of one batch; 4 waves each own 1/4 of KV (32 tiles of 32).
// No __syncthreads in the loop; phi/gT read directly from global (L2-resident:
// batch = bid&7 -> one batch per XCD, 2 MB < 4 MB L2). LDS only for the final
// log-sum-exp combine of the 4 waves' partial (m, l, O).
__global__ __launch_bounds__(256, 3) void k_attn(
    const unsigned short* __restrict__ theta, const unsigned short* __restrict__ phi,
    const unsigned short* __restrict__ gT, unsigned short* __restrict__ out_nm) {
  __shared__ float osum[32][132];
  __shared__ float mls[4][32][2];
  int bid = blockIdx.x;
  int b = bid & 7;                    // XCD-aware: batch per XCD
  int q0 = (bid >> 3) << 5;           // 32 q-rows per block
  int tid = threadIdx.x;
  int l = tid & 63, wid = tid >> 6, lr = l & 15, lg = l >> 4;

  const size_t tbase = ((size_t)b << 12) * 128;   // b*4096*128
  const unsigned short* pbase = phi + tbase;
  const unsigned short* vbase = gT + tbase;       // [128][4096] per batch

  Frag qf[2][4];
  for (int qq = 0; qq < 2; ++qq)
    for (int kc = 0; kc < 4; ++kc)
      qf[qq][kc].u = *(const ushort8*)(theta + tbase +
          (size_t)(q0 + qq * 16 + lr) * 128 + kc * 32 + 8 * lg);

  f32x4 oacc[2][8];
  for (int q = 0; q < 2; ++q) for (int d = 0; d < 8; ++d) oacc[q][d] = fz4();
  float m[2] = {-1e30f, -1e30f}, sden[2] = {0.f, 0.f};

  int kvlo = wid << 10;               // wave's private 1024-wide KV range

  for (int kt = 0; kt < 32; ++kt) {
    int kv0 = kvlo + kt * 32;

    // S^T = phi (A, direct from global) x theta (B): D[kv][q]
    f32x4 sacc[2][2];
    sacc[0][0] = fz4(); sacc[0][1] = fz4(); sacc[1][0] = fz4(); sacc[1][1] = fz4();
    for (int kc = 0; kc < 4; ++kc) {
      Frag a0, a1;
      a0.u = *(const ushort8*)(pbase + (size_t)(kv0 + lr) * 128 + kc * 32 + 8 * lg);
      a1.u = *(const ushort8*)(pbase + (size_t)(kv0 + 16 + lr) * 128 + kc * 32 + 8 * lg);
      sacc[0][0] = MFMA16(a0.b, qf[0][kc].b, sacc[0][0]);
      sacc[1][0] = MFMA16(a0.b, qf[1][kc].b, sacc[1][0]);
      sacc[0][1] = MFMA16(a1.b, qf[0][kc].b, sacc[0][1]);
      sacc[1][1] = MFMA16(a1.b, qf[1][kc].b, sacc[1][1]);
    }

    Frag bw[2];
    for (int qq = 0; qq < 2; ++qq) {
      float s[8];
      for (int j = 0; j < 4; ++j) { s[j] = sacc[qq][0][j]; s[4 + j] = sacc[qq][1][j]; }
      float mt = s[0];
      for (int j = 1; j < 8; ++j) mt = fmaxf(mt, s[j]);
      mt = fmaxf(mt, __shfl_xor(mt, 16));
      mt = fmaxf(mt, __shfl_xor(mt, 32));
      if (!__all(mt <= m[qq] + 8.0f)) {        // defer-rescale (T13)
        float mn = fmaxf(m[qq], mt);
        float sc = __expf(m[qq] - mn);
        sden[qq] *= sc;
        for (int dt = 0; dt < 8; ++dt) oacc[qq][dt] *= sc;
        m[qq] = mn;
      }
      float p[8], ps = 0.f;
      for (int j = 0; j < 8; ++j) { p[j] = __expf(s[j] - m[qq]); ps += p[j]; }
      ps += __shfl_xor(ps, 16);
      ps += __shfl_xor(ps, 32);
      sden[qq] += ps;
      // pack P (lane holds kv = 16*nb + 4*lg + j, q col = lr)
      unsigned int pw[4];
      for (int nb = 0; nb < 2; ++nb)
        for (int wd = 0; wd < 2; ++wd)
          pw[nb * 2 + wd] = (unsigned)f2bf(p[nb * 4 + 2 * wd]) |
                            ((unsigned)f2bf(p[nb * 4 + 2 * wd + 1]) << 16);
      // redistribute to B-frag layout: lane needs kv = 8*lg + e
      int src0 = lr | (((2 * lg) & 3) << 4);
      int src1 = lr | (((2 * lg + 1) & 3) << 4);
      int bt_ = lg >> 1;
      unsigned a0 = (unsigned)__shfl((int)pw[0], src0), a1 = (unsigned)__shfl((int)pw[1], src0),
               a2 = (unsigned)__shfl((int)pw[2], src0), a3 = (unsigned)__shfl((int)pw[3], src0);
      unsigned c0 = (unsigned)__shfl((int)pw[0], src1), c1 = (unsigned)__shfl((int)pw[1], src1),
               c2 = (unsigned)__shfl((int)pw[2], src1), c3 = (unsigned)__shfl((int)pw[3], src1);
      bw[qq].w[0] = bt_ ? a2 : a0;
      bw[qq].w[1] = bt_ ? a3 : a1;
      bw[qq].w[2] = bt_ ? c2 : c0;
      bw[qq].w[3] = bt_ ? c3 : c1;
    }

    // O^T += V^T (A, direct from global) x P^T (B): D[d][q]
    for (int dt = 0; dt < 8; ++dt) {
      Frag vf;
      vf.u = *(const ushort8*)(vbase + (size_t)(dt * 16 + lr) * 4096 + kv0 + 8 * lg);
      oacc[0][dt] = MFMA16(vf.b, bw[0].b, oacc[0][dt]);
      oacc[1][dt] = MFMA16(vf.b, bw[1].b, oacc[1][dt]);
    }
  }

  // ---- combine the 4 waves' partials (log-sum-exp merge) ----
  if (lg == 0) {
    mls[wid][lr][0] = m[0];      mls[wid][lr][1] = sden[0];
    mls[wid][16 + lr][0] = m[1]; mls[wid][16 + lr][1] = sden[1];
  }
  __syncthreads();
  float scale[2];
  for (int qq = 0; qq < 2; ++qq) {
    int row = qq * 16 + lr;
    float M = fmaxf(fmaxf(mls[0][row][0], mls[1][row][0]),
                    fmaxf(mls[2][row][0], mls[3][row][0]));
    scale[qq] = __expf(m[qq] - M);
  }
  for (int w = 0; w < 4; ++w) {
    if (wid == w) {
      for (int qq = 0; qq < 2; ++qq) {
        int row = qq * 16 + lr;
        float sc = scale[qq];
        for (int dt = 0; dt < 8; ++dt) {
          int d = dt * 16 + 4 * lg;
          if (w == 0) {
            for (int j = 0; j < 4; ++j) osum[row][d + j] = oacc[qq][dt][j] * sc;
          } else {
            for (int j = 0; j < 4; ++j) osum[row][d + j] += oacc[qq][dt][j] * sc;
          }
        }
      }
    }
    __syncthreads();
  }
  // write out: wave wid handles rows wid*8 .. wid*8+7
  {
    int row = wid * 8 + (l >> 3);
    int d0 = (l & 7) * 16;
    float M = fmaxf(fmaxf(mls[0][row][0], mls[1][row][0]),
                    fmaxf(mls[2][row][0], mls[3][row][0]));
    float Lt = 0.f;
    for (int w = 0; w < 4; ++w) Lt += mls[w][row][1] * __expf(mls[w][row][0] - M);
    float inv = 1.0f / Lt;
    ushort8 w1;
    for (int k = 0; k < 8; ++k) w1[k] = f2bf(osum[row][d0 + k] * inv);
    ushort8 w2;
    for (int k = 0; k < 8; ++k) w2[k] = f2bf(osum[row][d0 + 8 + k] * inv);
    size_t base = tbase + (size_t)(q0 + row) * 128 + d0;
    *(ushort8*)(out_nm + base) = w1;
    *(ushort8*)(out_nm + base + 8) = w2;
  }
}

// ---------------- mask GEMM + bias + relu + residual (fp32 out) ----------------
__global__ __launch_bounds__(256, 2) void k_mask(
    const unsigned short* __restrict__ wmb, const unsigned short* __restrict__ out_nm,
    const float* __restrict__ bm, const float* __restrict__ x,
    float* __restrict__ out) {
  int gb = blockIdx.x >> 6;
  size_t boff = (size_t)gb * 524288;
  int n0 = (blockIdx.x & 63) << 6;
  int tid = threadIdx.x;
  int l = tid & 63, w = tid >> 6, lr = l & 15, lg = l >> 4;
  int ob = w * 64;
  f32x4 acc[4][4];
  for (int i = 0; i < 4; ++i) for (int j = 0; j < 4; ++j) acc[i][j] = fz4();
  for (int kc = 0; kc < 4; ++kc) {
    int ko = kc * 32 + 8 * lg;
    Frag wa[4], xq[4];
    for (int ot = 0; ot < 4; ++ot)
      wa[ot].u = *(const ushort8*)(wmb + (size_t)(ob + ot * 16 + lr) * 128 + ko);
    for (int nt = 0; nt < 4; ++nt)
      xq[nt].u = *(const ushort8*)(out_nm + boff + (size_t)(n0 + nt * 16 + lr) * 128 + ko);
    for (int ot = 0; ot < 4; ++ot)
      for (int nt = 0; nt < 4; ++nt)
        acc[ot][nt] = MFMA16(wa[ot].b, xq[nt].b, acc[ot][nt]);
  }
  for (int ot = 0; ot < 4; ++ot) {
    int o0 = ob + ot * 16 + 4 * lg;
    for (int nt = 0; nt < 4; ++nt) {
      int n = n0 + nt * 16 + lr;
      for (int j = 0; j < 4; ++j) {
        size_t idx = ((size_t)(gb << 8) + o0 + j) * 4096 + n;
        float v = acc[ot][nt][j] + bm[o0 + j];
        v = v > 0.f ? v : 0.f;
        out[idx] = v + x[idx];
      }
    }
  }
}

extern "C" void kernel_launch(void* const* d_in, const int* in_sizes, int n_in,
                              void* d_out, int out_size, void* d_ws, size_t ws_size,
                              hipStream_t stream) {
  const float* x  = (const float*)d_in[0];
  const float* wg = (const float*)d_in[1];
  const float* bg = (const float*)d_in[2];
  const float* wt = (const float*)d_in[3];
  const float* bt = (const float*)d_in[4];
  const float* wp = (const float*)d_in[5];
  const float* bp = (const float*)d_in[6];
  const float* wm = (const float*)d_in[7];
  const float* bm = (const float*)d_in[8];
  float* out = (float*)d_out;           // fp32 output

  const size_t SLAB = 524288;           // ushorts per batch slab (1 MB)
  unsigned short* wcat  = (unsigned short*)d_ws;
  unsigned short* wmb   = wcat + 98304;
  unsigned short* theta = wmb + 32768;
  unsigned short* phi   = theta + 8 * SLAB;
  unsigned short* gT    = phi + 8 * SLAB;

  k_prep<<<384, 256, 0, stream>>>(wg, wt, wp, wm, wcat, wmb);
  k_proj_tp<<<512, 256, 0, stream>>>(x, wcat, bt, bp, theta, phi);
  k_proj_g<<<512, 256, 0, stream>>>(x, wcat, bg, gT);
  k_attn<<<1024, 256, 0, stream>>>(theta, phi, gT, theta /*alias: out_nm*/);
  k_mask<<<512, 256, 0, stream>>>(wmb, theta, bm, x, out);
}

// Round 7
// 301.908 us; speedup vs baseline: 1.4703x; 1.0533x over previous
//
#include <hip/hip_runtime.h>

// ---- types ----
typedef __bf16 bf16x8 __attribute__((ext_vector_type(8)));
typedef float f32x4 __attribute__((ext_vector_type(4)));
typedef unsigned short ushort8 __attribute__((ext_vector_type(8)));
typedef unsigned short ushort4v __attribute__((ext_vector_type(4)));
typedef unsigned int uint4v __attribute__((ext_vector_type(4)));

union Frag {
  ushort8 u;
  bf16x8 b;
  uint4v w;
};

__device__ __forceinline__ unsigned short f2bf(float f) {
  unsigned int u = __float_as_uint(f);
  u += 0x7fffu + ((u >> 16) & 1u);   // RNE; inputs are finite
  return (unsigned short)(u >> 16);
}

__device__ __forceinline__ f32x4 fz4() {
  f32x4 v; v[0] = 0.f; v[1] = 0.f; v[2] = 0.f; v[3] = 0.f; return v;
}

#define MFMA16(a, b, c) __builtin_amdgcn_mfma_f32_16x16x32_bf16(a, b, c, 0, 0, 0)

// Sizes: B=8, C=256, N=4096 (64x64), IC=128. OUTPUT FP32 (32 MiB).
// ws (ushort): wcat 98304 | wmb 32768 | theta 8*524288 | phi 8*524288 | gT 8*524288

// ---------------- prep: weights fp32 -> bf16 ----------------
__global__ void k_prep(const float* __restrict__ wg, const float* __restrict__ wt,
                       const float* __restrict__ wp, const float* __restrict__ wm,
                       unsigned short* __restrict__ wcat, unsigned short* __restrict__ wmb) {
  int t = blockIdx.x * 256 + threadIdx.x;
  if (t < 98304) {
    int o = t >> 8;
    const float* src = (o < 128) ? wt : ((o < 256) ? wp : wg);
    wcat[t] = f2bf(src[(o & 127) * 256 + (t & 255)]);
  }
  if (t < 32768) wmb[t] = f2bf(wm[t]);
}

// ---- shared staging: x[bx][c][pt0..pt0+64) -> xb[p][c] bf16, row stride 264 ----
__device__ __forceinline__ void stage_x(const float* __restrict__ x, int bx, int pt0,
                                        unsigned short* xb, int tid) {
  int c0 = (tid >> 2) * 4;
  int psub = (tid & 3) * 16;
  const float* xbase = x + (size_t)bx * 256 * 4096 + pt0;
  for (int ppc = 0; ppc < 4; ++ppc) {
    int p0 = psub + ppc * 4;
    f32x4 r0 = *(const f32x4*)(xbase + (size_t)(c0 + 0) * 4096 + p0);
    f32x4 r1 = *(const f32x4*)(xbase + (size_t)(c0 + 1) * 4096 + p0);
    f32x4 r2 = *(const f32x4*)(xbase + (size_t)(c0 + 2) * 4096 + p0);
    f32x4 r3 = *(const f32x4*)(xbase + (size_t)(c0 + 3) * 4096 + p0);
    for (int e = 0; e < 4; ++e) {
      ushort4v wv;
      wv[0] = f2bf(r0[e]); wv[1] = f2bf(r1[e]); wv[2] = f2bf(r2[e]); wv[3] = f2bf(r3[e]);
      *(ushort4v*)&xb[(p0 + e) * 264 + c0] = wv;
    }
  }
}

// ---------------- proj theta+phi ----------------
__global__ __launch_bounds__(256, 2) void k_proj_tp(
    const float* __restrict__ x, const unsigned short* __restrict__ wcat,
    const float* __restrict__ bt, const float* __restrict__ bp,
    unsigned short* __restrict__ theta, unsigned short* __restrict__ phi) {
  __shared__ unsigned short xb[64 * 264];
  int gb = blockIdx.x >> 6;
  size_t ob_off = (size_t)gb * 524288;
  int pt0 = (blockIdx.x & 63) << 6;
  int tid = threadIdx.x;
  stage_x(x, gb, pt0, xb, tid);
  __syncthreads();
  int l = tid & 63, w = tid >> 6, lr = l & 15, lg = l >> 4;
  int obase = w * 64;
  f32x4 acc[4][4];
  for (int i = 0; i < 4; ++i) for (int j = 0; j < 4; ++j) acc[i][j] = fz4();
  for (int kc = 0; kc < 8; ++kc) {
    int ko = kc * 32 + 8 * lg;
    Frag wa[4], xq[4];
    for (int ot = 0; ot < 4; ++ot)
      wa[ot].u = *(const ushort8*)(wcat + (size_t)(obase + ot * 16 + lr) * 256 + ko);
    for (int pt = 0; pt < 4; ++pt)
      xq[pt].u = *(const ushort8*)&xb[(pt * 16 + lr) * 264 + ko];
    for (int ot = 0; ot < 4; ++ot)
      for (int pt = 0; pt < 4; ++pt)
        acc[ot][pt] = MFMA16(wa[ot].b, xq[pt].b, acc[ot][pt]);
  }
  for (int ot = 0; ot < 4; ++ot) {
    int o0 = obase + ot * 16 + 4 * lg;   // D row = (lane>>4)*4 + reg
    float bias[4];
    for (int j = 0; j < 4; ++j) bias[j] = (o0 < 128) ? bt[o0 + j] : bp[o0 + j - 128];
    unsigned short* dst = (o0 < 128) ? theta : phi;
    int oc = o0 & 127;
    for (int pt = 0; pt < 4; ++pt) {
      int n = pt0 + pt * 16 + lr;        // D col = lane&15
      ushort4v wv;
      for (int j = 0; j < 4; ++j) {
        float v = acc[ot][pt][j] + bias[j];
        wv[j] = f2bf(v > 0.f ? v : 0.f);
      }
      *(ushort4v*)(dst + ob_off + (size_t)n * 128 + oc) = wv;
    }
  }
}

// ---------------- proj g (transposed out): gT[o][n] ----------------
__global__ __launch_bounds__(256, 2) void k_proj_g(
    const float* __restrict__ x, const unsigned short* __restrict__ wcat,
    const float* __restrict__ bg, unsigned short* __restrict__ gT) {
  __shared__ unsigned short xb[64 * 264];
  int gb = blockIdx.x >> 6;
  size_t ob_off = (size_t)gb * 524288;
  int pt0 = (blockIdx.x & 63) << 6;
  int tid = threadIdx.x;
  stage_x(x, gb, pt0, xb, tid);
  __syncthreads();
  int l = tid & 63, w = tid >> 6, lr = l & 15, lg = l >> 4;
  f32x4 acc[8];
  for (int i = 0; i < 8; ++i) acc[i] = fz4();
  for (int kc = 0; kc < 8; ++kc) {
    int ko = kc * 32 + 8 * lg;
    Frag xa;
    xa.u = *(const ushort8*)&xb[(w * 16 + lr) * 264 + ko];
    for (int ot = 0; ot < 8; ++ot) {
      Frag wb;
      wb.u = *(const ushort8*)(wcat + (size_t)(256 + ot * 16 + lr) * 256 + ko);
      acc[ot] = MFMA16(xa.b, wb.b, acc[ot]);
    }
  }
  for (int ot = 0; ot < 8; ++ot) {
    int o = ot * 16 + lr;                 // D col = channel
    float bias = bg[o];
    int n0 = pt0 + w * 16 + 4 * lg;       // D rows = position
    ushort4v wv;
    for (int j = 0; j < 4; ++j) {
      float v = acc[ot][j] + bias;
      wv[j] = f2bf(v > 0.f ? v : 0.f);
    }
    *(ushort4v*)(gT + ob_off + (size_t)o * 4096 + n0) = wv;
  }
}

// ---------------- fused flash attention, KV-split-4, reg-pipelined --------
// Block = 32 q-rows of one batch; 4 waves each own 1/4 of KV (32 tiles of 32).
// No barriers in loop. Software pipeline: V-loads issued before softmax
// (softmax covers their latency); next tile's phi prefetched during PV
// (PV + next S cover it). Unroll-by-2 with named buffers (no dyn indexing).
__global__ __launch_bounds__(256, 2) void k_attn(
    const unsigned short* __restrict__ theta, const unsigned short* __restrict__ phi,
    const unsigned short* __restrict__ gT, unsigned short* __restrict__ out_nm) {
  __shared__ float osum[32][132];
  __shared__ float mls[4][32][2];
  int bid = blockIdx.x;
  int b = bid & 7;                    // XCD-aware: batch per XCD
  int q0 = (bid >> 3) << 5;           // 32 q-rows per block
  int tid = threadIdx.x;
  int l = tid & 63, wid = tid >> 6, lr = l & 15, lg = l >> 4;

  const size_t tbase = ((size_t)b << 12) * 128;   // b*4096*128
  const unsigned short* pbase = phi + tbase;
  const unsigned short* vbase = gT + tbase;       // [128][4096] per batch

  Frag qf[2][4];
  for (int qq = 0; qq < 2; ++qq)
    for (int kc = 0; kc < 4; ++kc)
      qf[qq][kc].u = *(const ushort8*)(theta + tbase +
          (size_t)(q0 + qq * 16 + lr) * 128 + kc * 32 + 8 * lg);

  f32x4 oacc[2][8];
  for (int q = 0; q < 2; ++q) for (int d = 0; d < 8; ++d) oacc[q][d] = fz4();
  float m[2] = {-1e30f, -1e30f}, sden[2] = {0.f, 0.f};

  int kvlo = wid << 10;               // wave's private 1024-wide KV range

  Frag pa[2][4], pb[2][4], vt[8];

#define LOAD_PHI(DST, KV0)                                                        \
  do {                                                                            \
    const unsigned short* _pp = pbase + (size_t)((KV0) + lr) * 128 + 8 * lg;      \
    for (int kc = 0; kc < 4; ++kc) {                                              \
      DST[0][kc].u = *(const ushort8*)(_pp + kc * 32);                            \
      DST[1][kc].u = *(const ushort8*)(_pp + 16 * 128 + kc * 32);                 \
    }                                                                             \
  } while (0)

#define STEP(CUR, NXT, KV0)                                                       \
  do {                                                                            \
    int kv0 = (KV0);                                                              \
    f32x4 sacc[2][2];                                                             \
    sacc[0][0] = fz4(); sacc[0][1] = fz4(); sacc[1][0] = fz4(); sacc[1][1] = fz4();\
    for (int kc = 0; kc < 4; ++kc) {                                              \
      sacc[0][0] = MFMA16(CUR[0][kc].b, qf[0][kc].b, sacc[0][0]);                 \
      sacc[1][0] = MFMA16(CUR[0][kc].b, qf[1][kc].b, sacc[1][0]);                 \
      sacc[0][1] = MFMA16(CUR[1][kc].b, qf[0][kc].b, sacc[0][1]);                 \
      sacc[1][1] = MFMA16(CUR[1][kc].b, qf[1][kc].b, sacc[1][1]);                 \
    }                                                                             \
    /* issue V loads now; softmax below hides their latency */                    \
    for (int dt = 0; dt < 8; ++dt)                                                \
      vt[dt].u = *(const ushort8*)(vbase + (size_t)(dt * 16 + lr) * 4096 + kv0 + 8 * lg); \
    /* prefetch next phi tile; PV + next-S hide it */                             \
    LOAD_PHI(NXT, kv0 + 32);                                                      \
    Frag bw[2];                                                                   \
    for (int qq = 0; qq < 2; ++qq) {                                              \
      float s[8];                                                                 \
      for (int j = 0; j < 4; ++j) { s[j] = sacc[qq][0][j]; s[4 + j] = sacc[qq][1][j]; } \
      float mt = s[0];                                                            \
      for (int j = 1; j < 8; ++j) mt = fmaxf(mt, s[j]);                           \
      mt = fmaxf(mt, __shfl_xor(mt, 16));                                         \
      mt = fmaxf(mt, __shfl_xor(mt, 32));                                         \
      if (!__all(mt <= m[qq] + 8.0f)) {                                           \
        float mn = fmaxf(m[qq], mt);                                              \
        float sc = __expf(m[qq] - mn);                                            \
        sden[qq] *= sc;                                                           \
        for (int dt = 0; dt < 8; ++dt) oacc[qq][dt] *= sc;                        \
        m[qq] = mn;                                                               \
      }                                                                           \
      float p[8], ps = 0.f;                                                       \
      for (int j = 0; j < 8; ++j) { p[j] = __expf(s[j] - m[qq]); ps += p[j]; }    \
      ps += __shfl_xor(ps, 16);                                                   \
      ps += __shfl_xor(ps, 32);                                                   \
      sden[qq] += ps;                                                             \
      unsigned int pw[4];                                                         \
      for (int nb = 0; nb < 2; ++nb)                                              \
        for (int wd = 0; wd < 2; ++wd)                                            \
          pw[nb * 2 + wd] = (unsigned)f2bf(p[nb * 4 + 2 * wd]) |                  \
                            ((unsigned)f2bf(p[nb * 4 + 2 * wd + 1]) << 16);       \
      int src0 = lr | (((2 * lg) & 3) << 4);                                      \
      int src1 = lr | (((2 * lg + 1) & 3) << 4);                                  \
      int bt_ = lg >> 1;                                                          \
      unsigned a0 = (unsigned)__shfl((int)pw[0], src0), a1 = (unsigned)__shfl((int)pw[1], src0), \
               a2 = (unsigned)__shfl((int)pw[2], src0), a3 = (unsigned)__shfl((int)pw[3], src0); \
      unsigned c0 = (unsigned)__shfl((int)pw[0], src1), c1 = (unsigned)__shfl((int)pw[1], src1), \
               c2 = (unsigned)__shfl((int)pw[2], src1), c3 = (unsigned)__shfl((int)pw[3], src1); \
      bw[qq].w[0] = bt_ ? a2 : a0;                                                \
      bw[qq].w[1] = bt_ ? a3 : a1;                                                \
      bw[qq].w[2] = bt_ ? c2 : c0;                                                \
      bw[qq].w[3] = bt_ ? c3 : c1;                                                \
    }                                                                             \
    for (int dt = 0; dt < 8; ++dt) {                                              \
      oacc[0][dt] = MFMA16(vt[dt].b, bw[0].b, oacc[0][dt]);                       \
      oacc[1][dt] = MFMA16(vt[dt].b, bw[1].b, oacc[1][dt]);                       \
    }                                                                             \
  } while (0)

  LOAD_PHI(pa, kvlo);
  for (int kt = 0; kt < 32; kt += 2) {
    STEP(pa, pb, kvlo + kt * 32);
    STEP(pb, pa, kvlo + (kt + 1) * 32);   // last prefetch is a dead in-bounds load
  }
#undef STEP
#undef LOAD_PHI

  // ---- combine the 4 waves' partials (log-sum-exp merge) ----
  if (lg == 0) {
    mls[wid][lr][0] = m[0];      mls[wid][lr][1] = sden[0];
    mls[wid][16 + lr][0] = m[1]; mls[wid][16 + lr][1] = sden[1];
  }
  __syncthreads();
  float scale[2];
  for (int qq = 0; qq < 2; ++qq) {
    int row = qq * 16 + lr;
    float M = fmaxf(fmaxf(mls[0][row][0], mls[1][row][0]),
                    fmaxf(mls[2][row][0], mls[3][row][0]));
    scale[qq] = __expf(m[qq] - M);
  }
  for (int w = 0; w < 4; ++w) {
    if (wid == w) {
      for (int qq = 0; qq < 2; ++qq) {
        int row = qq * 16 + lr;
        float sc = scale[qq];
        for (int dt = 0; dt < 8; ++dt) {
          int d = dt * 16 + 4 * lg;
          if (w == 0) {
            for (int j = 0; j < 4; ++j) osum[row][d + j] = oacc[qq][dt][j] * sc;
          } else {
            for (int j = 0; j < 4; ++j) osum[row][d + j] += oacc[qq][dt][j] * sc;
          }
        }
      }
    }
    __syncthreads();
  }
  // write out: wave wid handles rows wid*8 .. wid*8+7
  {
    int row = wid * 8 + (l >> 3);
    int d0 = (l & 7) * 16;
    float M = fmaxf(fmaxf(mls[0][row][0], mls[1][row][0]),
                    fmaxf(mls[2][row][0], mls[3][row][0]));
    float Lt = 0.f;
    for (int w = 0; w < 4; ++w) Lt += mls[w][row][1] * __expf(mls[w][row][0] - M);
    float inv = 1.0f / Lt;
    ushort8 w1;
    for (int k = 0; k < 8; ++k) w1[k] = f2bf(osum[row][d0 + k] * inv);
    ushort8 w2;
    for (int k = 0; k < 8; ++k) w2[k] = f2bf(osum[row][d0 + 8 + k] * inv);
    size_t base = tbase + (size_t)(q0 + row) * 128 + d0;
    *(ushort8*)(out_nm + base) = w1;
    *(ushort8*)(out_nm + base + 8) = w2;
  }
}

// ---------------- mask GEMM + bias + relu + residual (fp32 out) ----------------
__global__ __launch_bounds__(256, 2) void k_mask(
    const unsigned short* __restrict__ wmb, const unsigned short* __restrict__ out_nm,
    const float* __restrict__ bm, const float* __restrict__ x,
    float* __restrict__ out) {
  int gb = blockIdx.x >> 6;
  size_t boff = (size_t)gb * 524288;
  int n0 = (blockIdx.x & 63) << 6;
  int tid = threadIdx.x;
  int l = tid & 63, w = tid >> 6, lr = l & 15, lg = l >> 4;
  int ob = w * 64;
  f32x4 acc[4][4];
  for (int i = 0; i < 4; ++i) for (int j = 0; j < 4; ++j) acc[i][j] = fz4();
  for (int kc = 0; kc < 4; ++kc) {
    int ko = kc * 32 + 8 * lg;
    Frag wa[4], xq[4];
    for (int ot = 0; ot < 4; ++ot)
      wa[ot].u = *(const ushort8*)(wmb + (size_t)(ob + ot * 16 + lr) * 128 + ko);
    for (int nt = 0; nt < 4; ++nt)
      xq[nt].u = *(const ushort8*)(out_nm + boff + (size_t)(n0 + nt * 16 + lr) * 128 + ko);
    for (int ot = 0; ot < 4; ++ot)
      for (int nt = 0; nt < 4; ++nt)
        acc[ot][nt] = MFMA16(wa[ot].b, xq[nt].b, acc[ot][nt]);
  }
  for (int ot = 0; ot < 4; ++ot) {
    int o0 = ob + ot * 16 + 4 * lg;
    for (int nt = 0; nt < 4; ++nt) {
      int n = n0 + nt * 16 + lr;
      for (int j = 0; j < 4; ++j) {
        size_t idx = ((size_t)(gb << 8) + o0 + j) * 4096 + n;
        float v = acc[ot][nt][j] + bm[o0 + j];
        v = v > 0.f ? v : 0.f;
        out[idx] = v + x[idx];
      }
    }
  }
}

extern "C" void kernel_launch(void* const* d_in, const int* in_sizes, int n_in,
                              void* d_out, int out_size, void* d_ws, size_t ws_size,
                              hipStream_t stream) {
  const float* x  = (const float*)d_in[0];
  const float* wg = (const float*)d_in[1];
  const float* bg = (const float*)d_in[2];
  const float* wt = (const float*)d_in[3];
  const float* bt = (const float*)d_in[4];
  const float* wp = (const float*)d_in[5];
  const float* bp = (const float*)d_in[6];
  const float* wm = (const float*)d_in[7];
  const float* bm = (const float*)d_in[8];
  float* out = (float*)d_out;           // fp32 output

  const size_t SLAB = 524288;           // ushorts per batch slab (1 MB)
  unsigned short* wcat  = (unsigned short*)d_ws;
  unsigned short* wmb   = wcat + 98304;
  unsigned short* theta = wmb + 32768;
  unsigned short* phi   = theta + 8 * SLAB;
  unsigned short* gT    = phi + 8 * SLAB;

  k_prep<<<384, 256, 0, stream>>>(wg, wt, wp, wm, wcat, wmb);
  k_proj_tp<<<512, 256, 0, stream>>>(x, wcat, bt, bp, theta, phi);
  k_proj_g<<<512, 256, 0, stream>>>(x, wcat, bg, gT);
  k_attn<<<1024, 256, 0, stream>>>(theta, phi, gT, theta /*alias: out_nm*/);
  k_mask<<<512, 256, 0, stream>>>(wmb, theta, bm, x, out);
}